// Round 2
// baseline (487.840 us; speedup 1.0000x reference)
//
#include <hip/hip_runtime.h>
#include <math.h>

#define N 4096
#define D 256
#define NPOS 32768
#define TEMP 0.07f
#define INVT (1.0f / 0.07f)

#define BM 64      // tile rows/cols
#define KB 32      // k-chunk
#define NT (N / BM) // 64 tiles per dim

// workspace layout (floats):
// [0..N)    expsum
// [N..2N)   dmin (float bits, via int atomicMin; d>=0 so IEEE-int order works)
// [2N..3N)  t = TEMP*log(expsum) - dmin
// [3N]      loss accumulator
#define WS_EXPSUM 0
#define WS_MIN    N
#define WS_T      (2 * N)
#define WS_ACC    (3 * N)

__global__ void init_ws_k(float* ws) {
    int i = blockIdx.x * 256 + threadIdx.x;
    if (i < N) {
        ws[WS_EXPSUM + i] = 0.0f;
        ((int*)ws)[WS_MIN + i] = 0x7F7FFFFF;  // FLT_MAX bits
    }
    if (i == 0) ws[WS_ACC] = 0.0f;
}

// MODE 0: per-row/col min of L1 distance (diag excluded) -> atomicMin
// MODE 1: per-row/col sum of exp((dmin - d)/T) (diag excluded) -> atomicAdd
template <int MODE>
__global__ __launch_bounds__(256)
void dist_tile_k(const float* __restrict__ x, float* __restrict__ ws) {
    const int bm = blockIdx.x;
    const int bn = blockIdx.y;
    if (bn < bm) return;  // upper triangle only (d symmetric)
    const bool diag = (bm == bn);

    const int tid = threadIdx.x;
    const int tx = tid & 15;   // column group 0..15
    const int ty = tid >> 4;   // row group 0..15

    __shared__ float As[KB][BM];  // [k][m] transposed
    __shared__ float Bs[KB][BM];

    float acc[4][4];
#pragma unroll
    for (int i = 0; i < 4; ++i)
#pragma unroll
        for (int j = 0; j < 4; ++j) acc[i][j] = 0.0f;

    const int rowA0 = bm * BM;
    const int rowB0 = bn * BM;

    const int lr = tid >> 3;          // 0..31  (row within half-tile)
    const int lk = (tid & 7) * 4;     // 0,4,...,28 (k group)

    for (int k0 = 0; k0 < D; k0 += KB) {
#pragma unroll
        for (int h = 0; h < 2; ++h) {
            const int rr = lr + 32 * h;
            const float4 va = *(const float4*)&x[(rowA0 + rr) * D + k0 + lk];
            As[lk + 0][rr] = va.x; As[lk + 1][rr] = va.y;
            As[lk + 2][rr] = va.z; As[lk + 3][rr] = va.w;
            const float4 vb = *(const float4*)&x[(rowB0 + rr) * D + k0 + lk];
            Bs[lk + 0][rr] = vb.x; Bs[lk + 1][rr] = vb.y;
            Bs[lk + 2][rr] = vb.z; Bs[lk + 3][rr] = vb.w;
        }
        __syncthreads();

#pragma unroll
        for (int k = 0; k < KB; ++k) {
            const float4 a4 = *(const float4*)&As[k][ty * 4];
            const float4 b4 = *(const float4*)&Bs[k][tx * 4];
            const float av[4] = {a4.x, a4.y, a4.z, a4.w};
            const float bv[4] = {b4.x, b4.y, b4.z, b4.w};
#pragma unroll
            for (int i = 0; i < 4; ++i)
#pragma unroll
                for (int j = 0; j < 4; ++j)
                    acc[i][j] += fabsf(av[i] - bv[j]);
        }
        __syncthreads();
    }

    __shared__ float redR[BM][17];
    __shared__ float redC[BM][17];

    if (MODE == 0) {
        // -------- min pass --------
        float rmin[4] = {3.4e38f, 3.4e38f, 3.4e38f, 3.4e38f};
        float cmin[4] = {3.4e38f, 3.4e38f, 3.4e38f, 3.4e38f};
#pragma unroll
        for (int i = 0; i < 4; ++i) {
#pragma unroll
            for (int j = 0; j < 4; ++j) {
                const int gi = rowA0 + ty * 4 + i;
                const int gj = rowB0 + tx * 4 + j;
                const float d = (gi == gj) ? 3.4e38f : acc[i][j];
                rmin[i] = fminf(rmin[i], d);
                cmin[j] = fminf(cmin[j], d);
            }
        }
#pragma unroll
        for (int i = 0; i < 4; ++i) redR[ty * 4 + i][tx] = rmin[i];
#pragma unroll
        for (int j = 0; j < 4; ++j) redC[tx * 4 + j][ty] = cmin[j];
        __syncthreads();

        int* minws = (int*)ws + WS_MIN;
        if (tid < BM) {
            float s = 3.4e38f;
#pragma unroll
            for (int t = 0; t < 16; ++t) s = fminf(s, redR[tid][t]);
            atomicMin(&minws[rowA0 + tid], __float_as_int(s));
        } else if (tid < 2 * BM && !diag) {
            const int c = tid - BM;
            float s = 3.4e38f;
#pragma unroll
            for (int t = 0; t < 16; ++t) s = fminf(s, redC[c][t]);
            atomicMin(&minws[rowB0 + c], __float_as_int(s));
        }
    } else {
        // -------- expsum pass --------
        const int* minws = (const int*)ws + WS_MIN;
        float dminR[4], dminC[4];
#pragma unroll
        for (int i = 0; i < 4; ++i) dminR[i] = __int_as_float(minws[rowA0 + ty * 4 + i]);
#pragma unroll
        for (int j = 0; j < 4; ++j) dminC[j] = __int_as_float(minws[rowB0 + tx * 4 + j]);

        float rsum[4] = {0.f, 0.f, 0.f, 0.f};
        float csum[4] = {0.f, 0.f, 0.f, 0.f};
#pragma unroll
        for (int i = 0; i < 4; ++i) {
#pragma unroll
            for (int j = 0; j < 4; ++j) {
                const int gi = rowA0 + ty * 4 + i;
                const int gj = rowB0 + tx * 4 + j;
                const float d = acc[i][j];
                if (gi != gj) {
                    rsum[i] += expf((dminR[i] - d) * INVT);
                    csum[j] += expf((dminC[j] - d) * INVT);
                }
            }
        }
#pragma unroll
        for (int i = 0; i < 4; ++i) redR[ty * 4 + i][tx] = rsum[i];
#pragma unroll
        for (int j = 0; j < 4; ++j) redC[tx * 4 + j][ty] = csum[j];
        __syncthreads();

        float* expsum = ws + WS_EXPSUM;
        if (tid < BM) {
            float s = 0.f;
#pragma unroll
            for (int t = 0; t < 16; ++t) s += redR[tid][t];
            atomicAdd(&expsum[rowA0 + tid], s);
        } else if (tid < 2 * BM && !diag) {
            const int c = tid - BM;
            float s = 0.f;
#pragma unroll
            for (int t = 0; t < 16; ++t) s += redC[c][t];
            atomicAdd(&expsum[rowB0 + c], s);
        }
    }
}

__global__ void trow_k(float* __restrict__ ws) {
    const int i = blockIdx.x * 256 + threadIdx.x;
    if (i < N) {
        const float es = ws[WS_EXPSUM + i];
        const float dmin = __int_as_float(((const int*)ws)[WS_MIN + i]);
        ws[WS_T + i] = TEMP * logf(es) - dmin;
    }
}

// 256 blocks x 4 waves; each wave handles 32 pairs sequentially.
__global__ __launch_bounds__(256)
void pair_k(const float* __restrict__ x, const int* __restrict__ row,
            const int* __restrict__ col, const float* __restrict__ ws,
            float* __restrict__ acc) {
    const int lane = threadIdx.x & 63;
    const int wave = threadIdx.x >> 6;
    const float* t = ws + WS_T;
    float wsum = 0.0f;
    for (int it = 0; it < 32; ++it) {
        const int p = blockIdx.x * 128 + wave * 32 + it;
        const int r = row[p];
        const int c = col[p];
        const float4 a = *(const float4*)&x[r * D + lane * 4];
        const float4 b = *(const float4*)&x[c * D + lane * 4];
        float d = fabsf(a.x - b.x) + fabsf(a.y - b.y) +
                  fabsf(a.z - b.z) + fabsf(a.w - b.w);
#pragma unroll
        for (int off = 32; off > 0; off >>= 1) d += __shfl_xor(d, off, 64);
        if (lane == 0) wsum += d + t[r];
    }
    if (lane == 0) atomicAdd(acc, wsum);
}

__global__ void finalize_k(const float* __restrict__ acc, float* __restrict__ out) {
    if (threadIdx.x == 0 && blockIdx.x == 0)
        out[0] = acc[0] * (1.0f / (float)NPOS);
}

extern "C" void kernel_launch(void* const* d_in, const int* in_sizes, int n_in,
                              void* d_out, int out_size, void* d_ws, size_t ws_size,
                              hipStream_t stream) {
    const float* x = (const float*)d_in[0];
    const int* row = (const int*)d_in[1];
    const int* col = (const int*)d_in[2];
    float* ws = (float*)d_ws;
    float* out = (float*)d_out;

    init_ws_k<<<(N + 255) / 256, 256, 0, stream>>>(ws);

    dim3 grid(NT, NT);
    dist_tile_k<0><<<grid, 256, 0, stream>>>(x, ws);   // min pass
    dist_tile_k<1><<<grid, 256, 0, stream>>>(x, ws);   // expsum pass

    trow_k<<<N / 256, 256, 0, stream>>>(ws);

    pair_k<<<NPOS / 128, 256, 0, stream>>>(x, row, col, ws, ws + WS_ACC);

    finalize_k<<<1, 64, 0, stream>>>(ws + WS_ACC, out);
}